// Round 13
// baseline (360.287 us; speedup 1.0000x reference)
//
#include <hip/hip_runtime.h>
#include <hip/hip_bf16.h>

#define B_  2048
#define L_  200
#define D_  128
#define H0_ 80
#define H1_ 40
#define NTILE 13           // 16-row score tiles per batch (208 rows, 8 pad)

typedef __attribute__((ext_vector_type(8))) short short8;
typedef __attribute__((ext_vector_type(4))) float floatx4;

__device__ __forceinline__ short f2bf(float f) {
    unsigned u = __float_as_uint(f);
    u += 0x7fffu + ((u >> 16) & 1u);   // round-to-nearest-even
    return (short)(u >> 16);
}
__device__ __forceinline__ float bf2f(short s) {
    return __uint_as_float(((unsigned)(unsigned short)s) << 16);
}

// ---------------- fused: one batch per block, NO WORKSPACE ------------------
// All weight transforms computed in-block from fp32 W0/W1 (L2-resident):
//   W0eff[d][h] = bf16( bf16(W0a+W0c)[d][h] + tgt[d]*bf16(W0d)[d][h] )  (K=128)
//   beff[h]     = b0[h] + sum_d tgt[d]*bf16(W0b-W0c)[d][h]
//   w1f         = bf16(W1) fragments, zero-padded to 48x96
// Rounding bit-replicates the previous prep_kernel -> identical numerics.
// grid 2048; LDS ~34.8 KB -> 4 blocks/CU.
__global__ __launch_bounds__(256, 2) void fused_kernel(
    const float* __restrict__ hist, const float* __restrict__ tgt,
    const int* __restrict__ mask, const float* __restrict__ W0,
    const float* __restrict__ b0p, const float* __restrict__ W1,
    const float* __restrict__ b1, const float* __restrict__ W2,
    const float* __restrict__ b2, float* __restrict__ out)
{
    __shared__ __align__(16) short wbuf[10560];      // W0eff [80][132], 21120 B
    __shared__ __align__(16) short h0t[4][16][100];  // 12800 B; tail aliases pw[4][128] f32
    __shared__ float tgs[D_];                        // 512 B
    __shared__ float beffs[H0_];                     // 320 B
    __shared__ float scores[208];                    // 832 B; aliases beff partials; then attn_w
    __shared__ float red[8];
    // total 35616 B -> 4 blocks/CU

    const int tid = threadIdx.x;
    const int wave = tid >> 6, lane = tid & 63;
    const int col = lane & 15, quad = lane >> 4;
    const int b = blockIdx.x;

    // ---- prologue: stage tgt, zero h0t k-tail, build w1 frags from fp32 W1 ----
    if (tid < D_) tgs[tid] = tgt[(size_t)b * D_ + tid];
    if (tid < 128) {                                      // zero h0t cols 80..95
        int w = tid >> 5, row = (tid >> 1) & 15, c = 80 + (tid & 1) * 8;
        *(short8*)&h0t[w][row][c] = (short8)0;
    }
    short8 w1f[3][3];
    #pragma unroll
    for (int ks = 0; ks < 3; ++ks)
        #pragma unroll
        for (int nt = 0; nt < 3; ++nt) {
            const int n = nt * 16 + col;
            short8 f;
            #pragma unroll
            for (int j = 0; j < 8; ++j) {
                const int k = ks * 32 + quad * 8 + j;
                f[j] = (n < H1_ && k < H0_) ? f2bf(W1[(size_t)k * H1_ + n]) : (short)0;
            }
            w1f[ks][nt] = f;
        }
    float b1r[3], w2r[3];
    #pragma unroll
    for (int nt = 0; nt < 3; ++nt) {
        int h = nt * 16 + col;
        b1r[nt] = (h < H1_) ? b1[h] : 0.f;
        w2r[nt] = (h < H1_) ? W2[h] : 0.f;
    }
    const float b2v = b2[0];
    __syncthreads();                                      // tgs ready

    // ---- build W0eff in LDS from fp32 W0 (coalesced reads, transposed loop) ----
    for (int i = tid; i < 1280; i += 256) {               // i -> (d, h-group of 8)
        const int d = i / 10, hh = (i - d * 10) * 8;
        const float t = tgs[d];
        floatx4 a0 = *(const floatx4*)(W0 + (size_t)d * H0_ + hh);
        floatx4 a1 = *(const floatx4*)(W0 + (size_t)d * H0_ + hh + 4);
        floatx4 c0 = *(const floatx4*)(W0 + (size_t)(256 + d) * H0_ + hh);
        floatx4 c1 = *(const floatx4*)(W0 + (size_t)(256 + d) * H0_ + hh + 4);
        floatx4 p0 = *(const floatx4*)(W0 + (size_t)(384 + d) * H0_ + hh);
        floatx4 p1 = *(const floatx4*)(W0 + (size_t)(384 + d) * H0_ + hh + 4);
        #pragma unroll
        for (int j = 0; j < 4; ++j) {
            short wa = f2bf(a0[j] + c0[j]);               // replicate prep rounding
            short wd = f2bf(p0[j]);
            wbuf[(hh + j) * 132 + d] = f2bf(bf2f(wa) + t * bf2f(wd));
            short wa2 = f2bf(a1[j] + c1[j]);
            short wd2 = f2bf(p1[j]);
            wbuf[(hh + 4 + j) * 132 + d] = f2bf(bf2f(wa2) + t * bf2f(wd2));
        }
    }
    // ---- beff partials from fp32 W0 (coalesced in h across threads) ----
    float* red2 = &scores[0];                             // [2][80], freed before scores
    if (tid < 160) {
        int seg = tid / 80, h = tid - seg * 80;
        int d0 = seg * 64;
        float s = 0.f;
        #pragma unroll 8
        for (int d = d0; d < d0 + 64; ++d) {
            short w = f2bf(W0[(size_t)(128 + d) * H0_ + h] - W0[(size_t)(256 + d) * H0_ + h]);
            s += tgs[d] * bf2f(w);
        }
        red2[seg * 80 + h] = s;
    }
    __syncthreads();                                      // wbuf + partials ready
    if (tid < H0_) beffs[tid] = b0p[tid] + red2[tid] + red2[80 + tid];
    __syncthreads();                                      // beffs ready

    // ---- per-lane hoists (tile-invariant) ----
    float ber[5];
    #pragma unroll
    for (int nt = 0; nt < 5; ++nt) ber[nt] = beffs[nt * 16 + col];

    // ---- score phase: 13 tiles over 4 waves ----
    for (int t = wave; t < NTILE; t += 4) {
        const int l = t * 16 + col;
        const int lc = (l < L_) ? l : (L_ - 1);           // clamp pad rows (masked later)
        const float* ap = hist + ((size_t)b * L_ + lc) * D_ + quad * 8;

        floatx4 A[8];
        #pragma unroll
        for (int u = 0; u < 8; ++u)
            A[u] = *(const floatx4*)(ap + (u >> 1) * 32 + (u & 1) * 4);

        short8 ah[4];
        #pragma unroll
        for (int ks = 0; ks < 4; ++ks) {
            short8 h8;
            #pragma unroll
            for (int j = 0; j < 8; ++j) h8[j] = f2bf(A[2 * ks + (j >> 2)][j & 3]);
            ah[ks] = h8;
        }

        // layer 0: K=128 against per-batch W0eff (B-frags from LDS)
        floatx4 c0[5];
        #pragma unroll
        for (int nt = 0; nt < 5; ++nt) c0[nt] = (floatx4)0.f;
        #pragma unroll
        for (int ks = 0; ks < 4; ++ks)
            #pragma unroll
            for (int nt = 0; nt < 5; ++nt) {
                short8 bfr = *(const short8*)(wbuf + (nt * 16 + col) * 132 + ks * 32 + quad * 8);
                c0[nt] = __builtin_amdgcn_mfma_f32_16x16x32_bf16(ah[ks], bfr, c0[nt], 0, 0, 0);
            }

        // bias+relu -> wave-private h0 tile
        #pragma unroll
        for (int nt = 0; nt < 5; ++nt) {
            #pragma unroll
            for (int r = 0; r < 4; ++r) {
                float v = c0[nt][r] + ber[nt];
                v = v > 0.f ? v : 0.f;
                h0t[wave][quad * 4 + r][nt * 16 + col] = f2bf(v);
            }
        }

        // layer 1 (w1 frags in regs)
        floatx4 c1[3];
        #pragma unroll
        for (int nt = 0; nt < 3; ++nt) c1[nt] = (floatx4)0.f;
        #pragma unroll
        for (int ks = 0; ks < 3; ++ks) {
            short8 a1 = *(const short8*)&h0t[wave][col][ks * 32 + quad * 8];
            #pragma unroll
            for (int nt = 0; nt < 3; ++nt)
                c1[nt] = __builtin_amdgcn_mfma_f32_16x16x32_bf16(a1, w1f[ks][nt], c1[nt], 0, 0, 0);
        }

        // layer 2 + 16-lane reduce -> LDS scores
        float s4[4] = {0.f, 0.f, 0.f, 0.f};
        #pragma unroll
        for (int nt = 0; nt < 3; ++nt)
            #pragma unroll
            for (int r = 0; r < 4; ++r) {
                float v = c1[nt][r] + b1r[nt];
                v = v > 0.f ? v : 0.f;
                s4[r] += v * w2r[nt];
            }
        #pragma unroll
        for (int r = 0; r < 4; ++r) {
            s4[r] += __shfl_xor(s4[r], 1, 16);
            s4[r] += __shfl_xor(s4[r], 2, 16);
            s4[r] += __shfl_xor(s4[r], 4, 16);
            s4[r] += __shfl_xor(s4[r], 8, 16);
        }
        if (col == 0) {
            #pragma unroll
            for (int r = 0; r < 4; ++r)
                scores[t * 16 + quad * 4 + r] = s4[r] + b2v;
        }
    }
    __syncthreads();

    // ---- softmax (block-wide) ----
    float sc = -3.0e38f;
    if (tid < L_) {
        sc = scores[tid];
        if (mask[(size_t)b * L_ + tid] == 0) sc -= 1e9f;
    }
    float m = sc;
    #pragma unroll
    for (int off = 32; off >= 1; off >>= 1) m = fmaxf(m, __shfl_xor(m, off, 64));
    if (lane == 0) red[wave] = m;
    __syncthreads();
    m = fmaxf(fmaxf(red[0], red[1]), fmaxf(red[2], red[3]));
    float e = (tid < L_) ? __expf(sc - m) : 0.f;
    float s = e;
    #pragma unroll
    for (int off = 32; off >= 1; off >>= 1) s += __shfl_xor(s, off, 64);
    if (lane == 0) red[4 + wave] = s;
    __syncthreads();
    s = red[4] + red[5] + red[6] + red[7];
    float av = e * (1.0f / s);
    if (tid < L_) {
        scores[tid] = av;                                 // reuse as attn weights
        out[(size_t)B_ * D_ + (size_t)b * L_ + tid] = av;
    }
    __syncthreads();

    // ---- weighted sum: 4 waves x 50 rows, 2 rows/iter (float4/lane) ----
    float* pw = (float*)&h0t[0][0][0];                    // [4][128]
    {
        const int rsel = lane >> 5;                       // 0/1: which of the row pair
        const int d0 = (lane & 31) * 4;
        const int rbase = wave * 50;
        const float* hb = hist + ((size_t)b * L_ + rbase + rsel) * D_ + d0;
        floatx4 acc = (floatx4)0.f;
        #pragma unroll 25
        for (int i = 0; i < 25; ++i) {
            float w = scores[rbase + 2 * i + rsel];
            floatx4 h4 = *(const floatx4*)(hb + (size_t)(2 * i) * D_);
            acc.x = fmaf(w, h4.x, acc.x);
            acc.y = fmaf(w, h4.y, acc.y);
            acc.z = fmaf(w, h4.z, acc.z);
            acc.w = fmaf(w, h4.w, acc.w);
        }
        acc.x += __shfl_xor(acc.x, 32, 64);
        acc.y += __shfl_xor(acc.y, 32, 64);
        acc.z += __shfl_xor(acc.z, 32, 64);
        acc.w += __shfl_xor(acc.w, 32, 64);
        if (rsel == 0) *(floatx4*)&pw[wave * 128 + d0] = acc;
    }
    __syncthreads();
    if (tid < D_)
        out[(size_t)b * D_ + tid] = (pw[tid] + pw[128 + tid]) + (pw[256 + tid] + pw[384 + tid]);
}

extern "C" void kernel_launch(void* const* d_in, const int* in_sizes, int n_in,
                              void* d_out, int out_size, void* d_ws, size_t ws_size,
                              hipStream_t stream) {
    const float* hist = (const float*)d_in[0];
    const float* tgt  = (const float*)d_in[1];
    const int*   mask = (const int*)d_in[2];
    const float* W0   = (const float*)d_in[3];
    const float* b0   = (const float*)d_in[4];
    const float* W1   = (const float*)d_in[5];
    const float* b1   = (const float*)d_in[6];
    const float* W2   = (const float*)d_in[7];
    const float* b2   = (const float*)d_in[8];

    (void)d_ws; (void)ws_size;                            // workspace intentionally unused

    fused_kernel<<<B_, 256, 0, stream>>>(hist, tgt, mask, W0, b0, W1, b1, W2, b2,
                                         (float*)d_out);
}

// Round 14
// 330.860 us; speedup vs baseline: 1.0889x; 1.0889x over previous
//
#include <hip/hip_runtime.h>
#include <hip/hip_bf16.h>

#define B_  2048
#define L_  200
#define D_  128
#define H0_ 80
#define H1_ 40
#define NTILE 13           // 16-row score tiles per batch (208 rows, 8 pad)

// ws layout (shorts): Bg[80][256] @0 | w1t[48][96] @20480 | w0p[128][84] @25088
#define WS_BG  0
#define WS_W1T 20480
#define WS_W0P 25088
#define WS_TOT 35840

typedef __attribute__((ext_vector_type(8))) short short8;
typedef __attribute__((ext_vector_type(4))) float floatx4;

__device__ __forceinline__ short f2bf(float f) {
    unsigned u = __float_as_uint(f);
    u += 0x7fffu + ((u >> 16) & 1u);   // round-to-nearest-even
    return (short)(u >> 16);
}
__device__ __forceinline__ float bf2f(short s) {
    return __uint_as_float(((unsigned)(unsigned short)s) << 16);
}

// ---------------- prep: pure weight transform, one pass ---------------------
// feat@W0 = hist@(W0a+W0c) + (hist.*tgt)@W0d + [tgt@(W0b-W0c)+b0]
__global__ __launch_bounds__(256) void prep_kernel(
    const float* __restrict__ W0, const float* __restrict__ W1,
    short* __restrict__ ws)
{
    for (int i = blockIdx.x * 256 + threadIdx.x; i < WS_TOT; i += 64 * 256) {
        short v;
        if (i < WS_W1T) {                       // Bg[h][k]: k<128 W0a+W0c, k>=128 W0d
            int h = i >> 8, k = i & 255;
            float x = (k < 128) ? (W0[(size_t)k * H0_ + h] + W0[(size_t)(256 + k) * H0_ + h])
                                : W0[(size_t)(384 + (k - 128)) * H0_ + h];
            v = f2bf(x);
        } else if (i < WS_W0P) {                // w1t[n][k] 48x96, zero-padded
            int j = i - WS_W1T;
            int n = j / 96, k = j - n * 96;
            v = (n < H1_ && k < H0_) ? f2bf(W1[(size_t)k * H1_ + n]) : (short)0;
        } else {                                // w0p[d][h] 128x84 = bf16(W0b-W0c), padded
            int j = i - WS_W0P;
            int d = j / 84, h = j - d * 84;
            v = (h < H0_) ? f2bf(W0[(size_t)(128 + d) * H0_ + h] - W0[(size_t)(256 + d) * H0_ + h])
                          : (short)0;
        }
        ws[i] = v;
    }
}

// ---------------- fused: scores + ONLINE weighted sum (flash-style) ---------
// W0eff[b][d][h] = Bg1[h][d] + tgt[b][d]*Bg2[h][d]   (layer-0 K=128)
// Numerator of softmax-weighted hist accumulated online in the score phase
// from the already-loaded A registers; wsum phase and 2nd hist pass deleted.
__global__ __launch_bounds__(256, 2) void fused_kernel(
    const float* __restrict__ hist, const float* __restrict__ tgt,
    const int* __restrict__ mask, const short* __restrict__ ws,
    const float* __restrict__ b0p, const float* __restrict__ b1,
    const float* __restrict__ W2, const float* __restrict__ b2,
    float* __restrict__ out)
{
    __shared__ __align__(16) short wbuf[10560];      // W0eff [80][132], 21120 B
    __shared__ __align__(16) short h0t[4][16][100];  // 12800 B; post-score aliases pw[w][128] f32
    __shared__ float tgs[D_];                        // 512 B
    __shared__ float beffs[H0_];                     // 320 B
    __shared__ float scores[208];                    // 832 B; aliases beff partials
    __shared__ float red[8];
    __shared__ float mws[4];                         // per-wave running max
    __shared__ int   mks[200];                       // mask staged
    // total ~36.4 KB -> 4 blocks/CU

    const int tid = threadIdx.x;
    const int wave = tid >> 6, lane = tid & 63;
    const int col = lane & 15, quad = lane >> 4;
    const int b = blockIdx.x;

    // ---- prologue ----
    if (tid < D_) tgs[tid] = tgt[(size_t)b * D_ + tid];
    if (tid < 200) mks[tid] = mask[(size_t)b * L_ + tid];
    if (tid < 128) {                                      // zero h0t cols 80..95
        int w = tid >> 5, row = (tid >> 1) & 15, c = 80 + (tid & 1) * 8;
        *(short8*)&h0t[w][row][c] = (short8)0;
    }
    short8 w1f[3][3];
    #pragma unroll
    for (int ks = 0; ks < 3; ++ks)
        #pragma unroll
        for (int nt = 0; nt < 3; ++nt)
            w1f[ks][nt] = *(const short8*)(ws + WS_W1T + (nt * 16 + col) * 96 + ks * 32 + quad * 8);
    float b1r[3], w2r[3];
    #pragma unroll
    for (int nt = 0; nt < 3; ++nt) {
        int h = nt * 16 + col;
        b1r[nt] = (h < H1_) ? b1[h] : 0.f;
        w2r[nt] = (h < H1_) ? W2[h] : 0.f;
    }
    const float b2v = b2[0];
    __syncthreads();                                      // tgs ready

    // ---- build W0eff in LDS (Bg from L2) ----
    for (int i = tid; i < 1280; i += 256) {               // 80 rows x 16 chunks of 8
        int h = i >> 4, d0 = (i & 15) * 8;
        short8 wa = *(const short8*)(ws + WS_BG + h * 256 + d0);
        short8 wd = *(const short8*)(ws + WS_BG + h * 256 + 128 + d0);
        floatx4 t0 = *(const floatx4*)&tgs[d0];
        floatx4 t1 = *(const floatx4*)&tgs[d0 + 4];
        short8 o;
        #pragma unroll
        for (int j = 0; j < 4; ++j) o[j] = f2bf(bf2f(wa[j]) + t0[j] * bf2f(wd[j]));
        #pragma unroll
        for (int j = 4; j < 8; ++j) o[j] = f2bf(bf2f(wa[j]) + t1[j - 4] * bf2f(wd[j]));
        *(short8*)(wbuf + h * 132 + d0) = o;
    }
    // ---- beff partials (w0p direct from L2) ----
    float* red2 = &scores[0];                             // [2][80], freed before scores
    if (tid < 160) {
        int seg = tid / 80, h = tid - seg * 80;
        int d0 = seg * 64;
        float s = 0.f;
        #pragma unroll 8
        for (int d = d0; d < d0 + 64; ++d)
            s += tgs[d] * bf2f(ws[WS_W0P + d * 84 + h]);
        red2[seg * 80 + h] = s;
    }
    __syncthreads();
    if (tid < H0_) beffs[tid] = b0p[tid] + red2[tid] + red2[80 + tid];
    __syncthreads();                                      // beffs ready

    float ber[5];
    #pragma unroll
    for (int nt = 0; nt < 5; ++nt) ber[nt] = beffs[nt * 16 + col];

    // ---- score phase + online numerator: 13 tiles over 4 waves ----
    floatx4 acc8[8];
    #pragma unroll
    for (int u = 0; u < 8; ++u) acc8[u] = (floatx4)0.f;
    float m_w = -3.0e38f;

    for (int t = wave; t < NTILE; t += 4) {
        const int l = t * 16 + col;
        const int lc = (l < L_) ? l : (L_ - 1);           // clamp pad rows
        const float* ap = hist + ((size_t)b * L_ + lc) * D_ + quad * 8;

        floatx4 A[8];
        #pragma unroll
        for (int u = 0; u < 8; ++u)
            A[u] = *(const floatx4*)(ap + (u >> 1) * 32 + (u & 1) * 4);

        short8 ah[4];
        #pragma unroll
        for (int ks = 0; ks < 4; ++ks) {
            short8 h8;
            #pragma unroll
            for (int j = 0; j < 8; ++j) h8[j] = f2bf(A[2 * ks + (j >> 2)][j & 3]);
            ah[ks] = h8;
        }

        // layer 0: K=128 vs W0eff
        floatx4 c0[5];
        #pragma unroll
        for (int nt = 0; nt < 5; ++nt) c0[nt] = (floatx4)0.f;
        #pragma unroll
        for (int ks = 0; ks < 4; ++ks)
            #pragma unroll
            for (int nt = 0; nt < 5; ++nt) {
                short8 bfr = *(const short8*)(wbuf + (nt * 16 + col) * 132 + ks * 32 + quad * 8);
                c0[nt] = __builtin_amdgcn_mfma_f32_16x16x32_bf16(ah[ks], bfr, c0[nt], 0, 0, 0);
            }

        // bias+relu -> wave-private h0 tile
        #pragma unroll
        for (int nt = 0; nt < 5; ++nt) {
            #pragma unroll
            for (int r = 0; r < 4; ++r) {
                float v = c0[nt][r] + ber[nt];
                v = v > 0.f ? v : 0.f;
                h0t[wave][quad * 4 + r][nt * 16 + col] = f2bf(v);
            }
        }

        // layer 1
        floatx4 c1[3];
        #pragma unroll
        for (int nt = 0; nt < 3; ++nt) c1[nt] = (floatx4)0.f;
        #pragma unroll
        for (int ks = 0; ks < 3; ++ks) {
            short8 a1 = *(const short8*)&h0t[wave][col][ks * 32 + quad * 8];
            #pragma unroll
            for (int nt = 0; nt < 3; ++nt)
                c1[nt] = __builtin_amdgcn_mfma_f32_16x16x32_bf16(a1, w1f[ks][nt], c1[nt], 0, 0, 0);
        }

        // layer 2 + 16-lane reduce -> LDS scores (raw, incl. b2)
        float s4[4] = {0.f, 0.f, 0.f, 0.f};
        #pragma unroll
        for (int nt = 0; nt < 3; ++nt)
            #pragma unroll
            for (int r = 0; r < 4; ++r) {
                float v = c1[nt][r] + b1r[nt];
                v = v > 0.f ? v : 0.f;
                s4[r] += v * w2r[nt];
            }
        #pragma unroll
        for (int r = 0; r < 4; ++r) {
            s4[r] += __shfl_xor(s4[r], 1, 16);
            s4[r] += __shfl_xor(s4[r], 2, 16);
            s4[r] += __shfl_xor(s4[r], 4, 16);
            s4[r] += __shfl_xor(s4[r], 8, 16);
        }
        if (col == 0) {
            #pragma unroll
            for (int r = 0; r < 4; ++r)
                scores[t * 16 + quad * 4 + r] = s4[r] + b2v;
        }

        // ---- online numerator: this lane's row weight from same-wave LDS ----
        float sraw = scores[t * 16 + col];
        float se = (l < L_) ? (mks[lc] ? sraw : sraw - 1e9f) : -3.0e38f;
        float tm = se;
        #pragma unroll
        for (int off = 32; off >= 1; off >>= 1) tm = fmaxf(tm, __shfl_xor(tm, off, 64));
        float mnew = fmaxf(m_w, tm);
        float f = __expf(m_w - mnew);
        float wexp = __expf(se - mnew);
        #pragma unroll
        for (int u = 0; u < 8; ++u) {
            #pragma unroll
            for (int j = 0; j < 4; ++j)
                acc8[u][j] = acc8[u][j] * f + wexp * A[u][j];
        }
        m_w = mnew;
    }

    // ---- fold wave numerator over its 16 rows (cols), park in h0t[wave] ----
    #pragma unroll
    for (int u = 0; u < 8; ++u)
        #pragma unroll
        for (int j = 0; j < 4; ++j) {
            acc8[u][j] += __shfl_xor(acc8[u][j], 1, 16);
            acc8[u][j] += __shfl_xor(acc8[u][j], 2, 16);
            acc8[u][j] += __shfl_xor(acc8[u][j], 4, 16);
            acc8[u][j] += __shfl_xor(acc8[u][j], 8, 16);
        }
    {
        float* pwv = (float*)&h0t[wave][0][0];            // own region: no cross-wave hazard
        if (col == 0) {
            #pragma unroll
            for (int u = 0; u < 8; ++u)
                *(floatx4*)&pwv[quad * 8 + (u >> 1) * 32 + (u & 1) * 4] = acc8[u];
        }
        if (lane == 0) mws[wave] = m_w;
    }
    __syncthreads();

    // ---- softmax denominator + attn output (scores[] holds raw s) ----
    float sc = -3.0e38f;
    if (tid < L_) {
        sc = scores[tid];
        if (mks[tid] == 0) sc -= 1e9f;
    }
    float m = sc;
    #pragma unroll
    for (int off = 32; off >= 1; off >>= 1) m = fmaxf(m, __shfl_xor(m, off, 64));
    if (lane == 0) red[wave] = m;
    __syncthreads();
    m = fmaxf(fmaxf(red[0], red[1]), fmaxf(red[2], red[3]));
    float e = (tid < L_) ? __expf(sc - m) : 0.f;
    float s = e;
    #pragma unroll
    for (int off = 32; off >= 1; off >>= 1) s += __shfl_xor(s, off, 64);
    if (lane == 0) red[4 + wave] = s;
    __syncthreads();
    s = red[4] + red[5] + red[6] + red[7];
    const float inv = 1.0f / s;
    if (tid < L_)
        out[(size_t)B_ * D_ + (size_t)b * L_ + tid] = e * inv;

    // ---- user_interest = (sum_w pw_w * e^{mw_w - m}) * inv ----
    if (tid < D_) {
        float ui = 0.f;
        #pragma unroll
        for (int w2 = 0; w2 < 4; ++w2) {
            const float* pwv = (const float*)&h0t[w2][0][0];
            ui += pwv[tid] * __expf(mws[w2] - m);
        }
        out[(size_t)b * D_ + tid] = ui * inv;
    }
}

extern "C" void kernel_launch(void* const* d_in, const int* in_sizes, int n_in,
                              void* d_out, int out_size, void* d_ws, size_t ws_size,
                              hipStream_t stream) {
    const float* hist = (const float*)d_in[0];
    const float* tgt  = (const float*)d_in[1];
    const int*   mask = (const int*)d_in[2];
    const float* W0   = (const float*)d_in[3];
    const float* b0   = (const float*)d_in[4];
    const float* W1   = (const float*)d_in[5];
    const float* b1   = (const float*)d_in[6];
    const float* W2   = (const float*)d_in[7];
    const float* b2   = (const float*)d_in[8];

    short* ws = (short*)d_ws;

    prep_kernel<<<64, 256, 0, stream>>>(W0, W1, ws);
    fused_kernel<<<B_, 256, 0, stream>>>(hist, tgt, mask, ws, b0, b1, W2, b2,
                                         (float*)d_out);
}